// Round 1
// baseline (3655.743 us; speedup 1.0000x reference)
//
#include <hip/hip_runtime.h>

// GCN 3-layer: N=100000 nodes, E=1.6M edges, dims 128 -> 64 -> 64 -> 32.
// Pipeline per layer: h = X@W (GEMM, f32 vector ALU)
//                     agg = scatter_add(h[src] * dinv[src]*dinv[dst], dst)
//                     out = [relu](agg + dinv^2 * h + b)
// Scratch layout in d_ws: dinv[N] | P[N*64] | Q[N*64]  (~53 MB)

#define BLK 256

__global__ void deg_kernel(const int* __restrict__ dst, float* __restrict__ deg, int E) {
    int i = blockIdx.x * blockDim.x + threadIdx.x;
    if (i < E) unsafeAtomicAdd(&deg[dst[i]], 1.0f);
}

__global__ void dinv_kernel(float* __restrict__ deg_dinv, int N) {
    int i = blockIdx.x * blockDim.x + threadIdx.x;
    if (i < N) deg_dinv[i] = rsqrtf(deg_dinv[i] + 1.0f);
}

// Y[N,C] = X[N,K] @ W[K,C].  Each block: ROWS rows; each thread: RT rows x 4 cols.
// Xl padded to K+1 floats/row -> rg-stride banks spread (RT*(K+1) % 32 != 0).
template<int K, int C, int RT>
__global__ __launch_bounds__(256) void gemm_kernel(const float* __restrict__ X,
                                                   const float* __restrict__ W,
                                                   float* __restrict__ Y, int N) {
    constexpr int CG = C / 4;        // col groups (threads per row-group)
    constexpr int RG = 256 / CG;     // row groups
    constexpr int ROWS = RG * RT;    // rows per block
    __shared__ float Wl[K * C];
    __shared__ float Xl[ROWS * (K + 1)];
    const int tid = threadIdx.x;

    // stage W (float4)
    for (int i = tid; i < K * C / 4; i += 256)
        ((float4*)Wl)[i] = ((const float4*)W)[i];

    // stage X tile (float4 global load, scalar LDS stores due to +1 pad)
    const int row0 = blockIdx.x * ROWS;
    for (int idx = tid; idx < ROWS * (K / 4); idx += 256) {
        int r = idx / (K / 4), kc = idx % (K / 4);
        float4 v = make_float4(0.f, 0.f, 0.f, 0.f);
        int gr = row0 + r;
        if (gr < N) v = ((const float4*)X)[(size_t)gr * (K / 4) + kc];
        float* p = &Xl[r * (K + 1) + kc * 4];
        p[0] = v.x; p[1] = v.y; p[2] = v.z; p[3] = v.w;
    }
    __syncthreads();

    const int cg = tid % CG, rg = tid / CG;
    float acc[RT][4];
#pragma unroll
    for (int j = 0; j < RT; ++j)
#pragma unroll
        for (int c = 0; c < 4; ++c) acc[j][c] = 0.f;

#pragma unroll 4
    for (int k = 0; k < K; ++k) {
        float4 w = *(const float4*)&Wl[k * C + cg * 4];
#pragma unroll
        for (int j = 0; j < RT; ++j) {
            float xv = Xl[(rg * RT + j) * (K + 1) + k];
            acc[j][0] += xv * w.x;
            acc[j][1] += xv * w.y;
            acc[j][2] += xv * w.z;
            acc[j][3] += xv * w.w;
        }
    }

#pragma unroll
    for (int j = 0; j < RT; ++j) {
        int gr = row0 + rg * RT + j;
        if (gr < N)
            *(float4*)&Y[(size_t)gr * C + cg * 4] =
                make_float4(acc[j][0], acc[j][1], acc[j][2], acc[j][3]);
    }
}

// AGG[dst] += H[src] * dinv[src]*dinv[dst].  One thread per (edge, 4-feat chunk).
template<int C>
__global__ void edge_scatter(const int* __restrict__ src, const int* __restrict__ dst,
                             const float* __restrict__ dinv, const float* __restrict__ H,
                             float* __restrict__ AGG, int E) {
    constexpr int CH = C / 4;
    int gid = blockIdx.x * blockDim.x + threadIdx.x;
    int e = gid / CH;
    int c = gid % CH;
    if (e >= E) return;
    int s = src[e], d = dst[e];
    float norm = dinv[s] * dinv[d];
    float4 v = *(const float4*)&H[(size_t)s * C + c * 4];
    float* o = &AGG[(size_t)d * C + c * 4];
    unsafeAtomicAdd(o + 0, v.x * norm);
    unsafeAtomicAdd(o + 1, v.y * norm);
    unsafeAtomicAdd(o + 2, v.z * norm);
    unsafeAtomicAdd(o + 3, v.w * norm);
}

// OUT = [relu](AGG + dinv^2 * H + b)
template<int C, bool RELU>
__global__ void finalize_kernel(const float* __restrict__ AGG, const float* __restrict__ H,
                                const float* __restrict__ dinv, const float* __restrict__ bias,
                                float* __restrict__ OUT, int N) {
    constexpr int CH = C / 4;
    int gid = blockIdx.x * blockDim.x + threadIdx.x;
    int i = gid / CH;
    int c = gid % CH;
    if (i >= N) return;
    float di = dinv[i];
    float sl = di * di;
    float4 a = *(const float4*)&AGG[(size_t)i * C + c * 4];
    float4 h = *(const float4*)&H[(size_t)i * C + c * 4];
    float4 b = *(const float4*)&bias[c * 4];
    float4 r;
    r.x = a.x + sl * h.x + b.x;
    r.y = a.y + sl * h.y + b.y;
    r.z = a.z + sl * h.z + b.z;
    r.w = a.w + sl * h.w + b.w;
    if (RELU) {
        r.x = fmaxf(r.x, 0.f); r.y = fmaxf(r.y, 0.f);
        r.z = fmaxf(r.z, 0.f); r.w = fmaxf(r.w, 0.f);
    }
    *(float4*)&OUT[(size_t)i * C + c * 4] = r;
}

extern "C" void kernel_launch(void* const* d_in, const int* in_sizes, int n_in,
                              void* d_out, int out_size, void* d_ws, size_t ws_size,
                              hipStream_t stream) {
    const float* x  = (const float*)d_in[0];
    const int*   ei = (const int*)d_in[1];
    const float* W1 = (const float*)d_in[2];
    const float* b1 = (const float*)d_in[3];
    const float* W2 = (const float*)d_in[4];
    const float* b2 = (const float*)d_in[5];
    const float* W3 = (const float*)d_in[6];
    const float* b3 = (const float*)d_in[7];
    float* out = (float*)d_out;

    const int N = in_sizes[0] / 128;
    const int E = in_sizes[1] / 2;
    const int* src = ei;
    const int* dst = ei + E;

    char* wsb = (char*)d_ws;
    size_t offDinv = 0;
    size_t offP = (((size_t)N * 4) + 255) & ~(size_t)255;
    size_t offQ = offP + ((((size_t)N * 64 * 4) + 255) & ~(size_t)255);
    float* dinv = (float*)(wsb + offDinv);
    float* P = (float*)(wsb + offP);
    float* Q = (float*)(wsb + offQ);

    // degree -> dinv
    hipMemsetAsync(dinv, 0, (size_t)N * 4, stream);
    deg_kernel<<<(E + BLK - 1) / BLK, BLK, 0, stream>>>(dst, dinv, E);
    dinv_kernel<<<(N + BLK - 1) / BLK, BLK, 0, stream>>>(dinv, N);

    // ---- Layer 1: 128 -> 64, relu ----
    gemm_kernel<128, 64, 2><<<(N + 31) / 32, BLK, 0, stream>>>(x, W1, P, N);
    hipMemsetAsync(Q, 0, (size_t)N * 64 * 4, stream);
    edge_scatter<64><<<((size_t)E * 16 + BLK - 1) / BLK, BLK, 0, stream>>>(src, dst, dinv, P, Q, E);
    finalize_kernel<64, true><<<((size_t)N * 16 + BLK - 1) / BLK, BLK, 0, stream>>>(Q, P, dinv, b1, Q, N);

    // ---- Layer 2: 64 -> 64, relu ----
    gemm_kernel<64, 64, 4><<<(N + 63) / 64, BLK, 0, stream>>>(Q, W2, P, N);
    hipMemsetAsync(Q, 0, (size_t)N * 64 * 4, stream);
    edge_scatter<64><<<((size_t)E * 16 + BLK - 1) / BLK, BLK, 0, stream>>>(src, dst, dinv, P, Q, E);
    finalize_kernel<64, true><<<((size_t)N * 16 + BLK - 1) / BLK, BLK, 0, stream>>>(Q, P, dinv, b2, Q, N);

    // ---- Layer 3: 64 -> 32, no relu, write d_out ----
    gemm_kernel<64, 32, 4><<<(N + 127) / 128, BLK, 0, stream>>>(Q, W3, P, N);
    hipMemsetAsync(Q, 0, (size_t)N * 32 * 4, stream);
    edge_scatter<32><<<((size_t)E * 8 + BLK - 1) / BLK, BLK, 0, stream>>>(src, dst, dinv, P, Q, E);
    finalize_kernel<32, false><<<((size_t)N * 8 + BLK - 1) / BLK, BLK, 0, stream>>>(Q, P, dinv, b3, out, N);
}

// Round 3
// 656.178 us; speedup vs baseline: 5.5713x; 5.5713x over previous
//
#include <hip/hip_runtime.h>

// GCN 3-layer: N=100000 nodes, E=1.6M edges, dims 128 -> 64 -> 64 -> 32.
// Round 2 (resubmit after broker timeout): on-device CSR (counting sort by dst)
// + gather aggregation:
//   per layer: h = X@W (f32 vector GEMM)
//              out = [relu]( sum_{e: dst=d} norm_e * h[src_e] + dinv_d^2 * h[d] + b )
// CSR rebuilt every launch (same work per call -> graph-capture safe).
// ws: dinv | rowptr | degi | cursor | esrc | enorm | P | Q  (~66 MB)

#define BLK 256

__global__ void count_kernel(const int* __restrict__ dst, int* __restrict__ degi, int E) {
    int i = blockIdx.x * blockDim.x + threadIdx.x;
    if (i < E) atomicAdd(&degi[dst[i]], 1);
}

__global__ void dinv_kernel(const int* __restrict__ degi, float* __restrict__ dinv, int N) {
    int i = blockIdx.x * blockDim.x + threadIdx.x;
    if (i < N) dinv[i] = rsqrtf((float)degi[i] + 1.0f);
}

// Exclusive scan of degi[0..N) -> rowptr[0..N]; single block of 1024 threads.
__global__ __launch_bounds__(1024) void scan_kernel(const int* __restrict__ degi,
                                                    int* __restrict__ rowptr, int N) {
    __shared__ int ssum[1024];
    const int t = threadIdx.x;
    const int chunk = (N + 1023) / 1024;
    const int lo = t * chunk;
    const int hi = min(lo + chunk, N);
    int s = 0;
    for (int i = lo; i < hi; ++i) s += degi[i];
    ssum[t] = s;
    __syncthreads();
    // Hillis-Steele inclusive scan over the 1024 chunk sums
    for (int off = 1; off < 1024; off <<= 1) {
        int v = (t >= off) ? ssum[t - off] : 0;
        __syncthreads();
        ssum[t] += v;
        __syncthreads();
    }
    int base = (t == 0) ? 0 : ssum[t - 1];
    for (int i = lo; i < hi; ++i) { rowptr[i] = base; base += degi[i]; }
    if (hi == N) rowptr[N] = base;   // saturated threads all write the total
}

// Permute edges into CSR slots; store src index and precomputed norm.
__global__ void fill_kernel(const int* __restrict__ src, const int* __restrict__ dst,
                            const float* __restrict__ dinv, const int* __restrict__ rowptr,
                            int* __restrict__ cursor, int* __restrict__ esrc,
                            float* __restrict__ enorm, int E) {
    int e = blockIdx.x * blockDim.x + threadIdx.x;
    if (e >= E) return;
    int d = dst[e], s = src[e];
    int p = rowptr[d] + atomicAdd(&cursor[d], 1);
    esrc[p] = s;
    enorm[p] = dinv[s] * dinv[d];
}

// Y[N,C] = X[N,K] @ W[K,C].  Each block: ROWS rows; each thread: RT rows x 4 cols.
template<int K, int C, int RT>
__global__ __launch_bounds__(256) void gemm_kernel(const float* __restrict__ X,
                                                   const float* __restrict__ W,
                                                   float* __restrict__ Y, int N) {
    constexpr int CG = C / 4;        // col groups (threads per row-group)
    constexpr int RG = 256 / CG;     // row groups
    constexpr int ROWS = RG * RT;    // rows per block
    __shared__ float Wl[K * C];
    __shared__ float Xl[ROWS * (K + 1)];
    const int tid = threadIdx.x;

    for (int i = tid; i < K * C / 4; i += 256)
        ((float4*)Wl)[i] = ((const float4*)W)[i];

    const int row0 = blockIdx.x * ROWS;
    for (int idx = tid; idx < ROWS * (K / 4); idx += 256) {
        int r = idx / (K / 4), kc = idx % (K / 4);
        float4 v = make_float4(0.f, 0.f, 0.f, 0.f);
        int gr = row0 + r;
        if (gr < N) v = ((const float4*)X)[(size_t)gr * (K / 4) + kc];
        float* p = &Xl[r * (K + 1) + kc * 4];
        p[0] = v.x; p[1] = v.y; p[2] = v.z; p[3] = v.w;
    }
    __syncthreads();

    const int cg = tid % CG, rg = tid / CG;
    float acc[RT][4];
#pragma unroll
    for (int j = 0; j < RT; ++j)
#pragma unroll
        for (int c = 0; c < 4; ++c) acc[j][c] = 0.f;

#pragma unroll 4
    for (int k = 0; k < K; ++k) {
        float4 w = *(const float4*)&Wl[k * C + cg * 4];
#pragma unroll
        for (int j = 0; j < RT; ++j) {
            float xv = Xl[(rg * RT + j) * (K + 1) + k];
            acc[j][0] += xv * w.x;
            acc[j][1] += xv * w.y;
            acc[j][2] += xv * w.z;
            acc[j][3] += xv * w.w;
        }
    }

#pragma unroll
    for (int j = 0; j < RT; ++j) {
        int gr = row0 + rg * RT + j;
        if (gr < N)
            *(float4*)&Y[(size_t)gr * C + cg * 4] =
                make_float4(acc[j][0], acc[j][1], acc[j][2], acc[j][3]);
    }
}

// CSR gather aggregation, fused self-loop + bias (+relu).
// C lanes per node; blockDim 256 -> 256/C nodes per block.
template<int C, bool RELU>
__global__ __launch_bounds__(256) void agg_kernel(const float* __restrict__ H,
                                                  const int* __restrict__ rowptr,
                                                  const int* __restrict__ esrc,
                                                  const float* __restrict__ enorm,
                                                  const float* __restrict__ dinv,
                                                  const float* __restrict__ bias,
                                                  float* __restrict__ OUT, int N) {
    constexpr int NPB = 256 / C;
    const int f = threadIdx.x % C;                       // feature lane
    const int node = blockIdx.x * NPB + threadIdx.x / C;
    if (node >= N) return;
    const int lo = rowptr[node], hi = rowptr[node + 1];

    float a0 = 0.f, a1 = 0.f, a2 = 0.f, a3 = 0.f;
    int i = lo;
    for (; i + 4 <= hi; i += 4) {
        int s0 = esrc[i + 0], s1 = esrc[i + 1], s2 = esrc[i + 2], s3 = esrc[i + 3];
        float w0 = enorm[i + 0], w1 = enorm[i + 1], w2 = enorm[i + 2], w3 = enorm[i + 3];
        float h0 = H[(size_t)s0 * C + f];
        float h1 = H[(size_t)s1 * C + f];
        float h2 = H[(size_t)s2 * C + f];
        float h3 = H[(size_t)s3 * C + f];
        a0 = fmaf(h0, w0, a0);
        a1 = fmaf(h1, w1, a1);
        a2 = fmaf(h2, w2, a2);
        a3 = fmaf(h3, w3, a3);
    }
    for (; i < hi; ++i)
        a0 = fmaf(H[(size_t)esrc[i] * C + f], enorm[i], a0);

    float di = dinv[node];
    float r = (a0 + a1) + (a2 + a3)
            + di * di * H[(size_t)node * C + f]
            + bias[f];
    if (RELU) r = fmaxf(r, 0.f);
    OUT[(size_t)node * C + f] = r;
}

extern "C" void kernel_launch(void* const* d_in, const int* in_sizes, int n_in,
                              void* d_out, int out_size, void* d_ws, size_t ws_size,
                              hipStream_t stream) {
    const float* x  = (const float*)d_in[0];
    const int*   ei = (const int*)d_in[1];
    const float* W1 = (const float*)d_in[2];
    const float* b1 = (const float*)d_in[3];
    const float* W2 = (const float*)d_in[4];
    const float* b2 = (const float*)d_in[5];
    const float* W3 = (const float*)d_in[6];
    const float* b3 = (const float*)d_in[7];
    float* out = (float*)d_out;

    const int N = in_sizes[0] / 128;
    const int E = in_sizes[1] / 2;
    const int* src = ei;
    const int* dst = ei + E;

    auto align = [](size_t v) { return (v + 255) & ~(size_t)255; };
    char* wsb = (char*)d_ws;
    size_t off = 0;
    float* dinv   = (float*)(wsb + off); off += align((size_t)N * 4);
    int*   rowptr = (int*)  (wsb + off); off += align((size_t)(N + 1) * 4);
    int*   degi   = (int*)  (wsb + off); off += align((size_t)N * 4);
    int*   cursor = (int*)  (wsb + off); off += align((size_t)N * 4);
    int*   esrc   = (int*)  (wsb + off); off += align((size_t)E * 4);
    float* enorm  = (float*)(wsb + off); off += align((size_t)E * 4);
    float* P      = (float*)(wsb + off); off += align((size_t)N * 64 * 4);
    float* Q      = (float*)(wsb + off);

    // ---- CSR build ----
    hipMemsetAsync(degi, 0, (size_t)N * 4, stream);
    hipMemsetAsync(cursor, 0, (size_t)N * 4, stream);
    count_kernel<<<(E + BLK - 1) / BLK, BLK, 0, stream>>>(dst, degi, E);
    dinv_kernel<<<(N + BLK - 1) / BLK, BLK, 0, stream>>>(degi, dinv, N);
    scan_kernel<<<1, 1024, 0, stream>>>(degi, rowptr, N);
    fill_kernel<<<(E + BLK - 1) / BLK, BLK, 0, stream>>>(src, dst, dinv, rowptr, cursor,
                                                         esrc, enorm, E);

    // ---- Layer 1: 128 -> 64, relu ----
    gemm_kernel<128, 64, 2><<<(N + 31) / 32, BLK, 0, stream>>>(x, W1, P, N);
    agg_kernel<64, true><<<(N * 64 + BLK - 1) / BLK, BLK, 0, stream>>>(P, rowptr, esrc, enorm,
                                                                       dinv, b1, Q, N);

    // ---- Layer 2: 64 -> 64, relu ----
    gemm_kernel<64, 64, 4><<<(N + 63) / 64, BLK, 0, stream>>>(Q, W2, P, N);
    agg_kernel<64, true><<<(N * 64 + BLK - 1) / BLK, BLK, 0, stream>>>(P, rowptr, esrc, enorm,
                                                                       dinv, b2, Q, N);

    // ---- Layer 3: 64 -> 32, no relu, write d_out ----
    gemm_kernel<64, 32, 4><<<(N + 127) / 128, BLK, 0, stream>>>(Q, W3, P, N);
    agg_kernel<32, false><<<(N * 32 + BLK - 1) / BLK, BLK, 0, stream>>>(P, rowptr, esrc, enorm,
                                                                        dinv, b3, out, N);
}

// Round 4
// 504.617 us; speedup vs baseline: 7.2446x; 1.3003x over previous
//
#include <hip/hip_runtime.h>

// GCN 3-layer: N=100000 nodes, E=1.6M edges, dims 128 -> 64 -> 64 -> 32.
// Round 3: round-2 structure (CSR counting-sort + gather agg) with the
// single-block scan (161 us, 25% of runtime, occupancy 0.16%) replaced by a
// hierarchical 3-kernel scan (~10 us).
// ws: dinv | rowptr | degi | cursor | bsum | boff | esrc | enorm | P | Q

#define BLK 256
#define SCAN_CHUNK 1024   // nodes per scan block (256 threads x 4)

__global__ void count_kernel(const int* __restrict__ dst, int* __restrict__ degi, int E) {
    int i = blockIdx.x * blockDim.x + threadIdx.x;
    if (i < E) atomicAdd(&degi[dst[i]], 1);
}

__global__ void dinv_kernel(const int* __restrict__ degi, float* __restrict__ dinv, int N) {
    int i = blockIdx.x * blockDim.x + threadIdx.x;
    if (i < N) dinv[i] = rsqrtf((float)degi[i] + 1.0f);
}

// --- hierarchical scan: A) per-block reduce, B) scan block sums, C) local scan+offset ---
__global__ __launch_bounds__(256) void scanA_kernel(const int* __restrict__ degi,
                                                    int* __restrict__ bsum, int N) {
    const int t = threadIdx.x;
    const int base = blockIdx.x * SCAN_CHUNK + t * 4;
    int s = 0;
#pragma unroll
    for (int j = 0; j < 4; ++j) { int i = base + j; if (i < N) s += degi[i]; }
    __shared__ int red[256];
    red[t] = s;
    __syncthreads();
    for (int off = 128; off > 0; off >>= 1) {
        if (t < off) red[t] += red[t + off];
        __syncthreads();
    }
    if (t == 0) bsum[blockIdx.x] = red[0];
}

// NBLK <= 256. Exclusive scan of bsum -> boff; total -> rowptr[N].
__global__ __launch_bounds__(256) void scanB_kernel(const int* __restrict__ bsum,
                                                    int* __restrict__ boff,
                                                    int* __restrict__ rowptr_last, int NBLK) {
    __shared__ int sh[256];
    const int t = threadIdx.x;
    sh[t] = (t < NBLK) ? bsum[t] : 0;
    __syncthreads();
    for (int off = 1; off < 256; off <<= 1) {
        int u = (t >= off) ? sh[t - off] : 0;
        __syncthreads();
        sh[t] += u;
        __syncthreads();
    }
    if (t < NBLK) boff[t] = (t == 0) ? 0 : sh[t - 1];
    if (t == 0) *rowptr_last = sh[255];
}

__global__ __launch_bounds__(256) void scanC_kernel(const int* __restrict__ degi,
                                                    const int* __restrict__ boff,
                                                    int* __restrict__ rowptr, int N) {
    const int t = threadIdx.x;
    const int base = blockIdx.x * SCAN_CHUNK + t * 4;
    int loc[4];
    int s = 0;
#pragma unroll
    for (int j = 0; j < 4; ++j) {
        int i = base + j;
        loc[j] = (i < N) ? degi[i] : 0;
        s += loc[j];
    }
    __shared__ int sh[256];
    sh[t] = s;
    __syncthreads();
    for (int off = 1; off < 256; off <<= 1) {
        int u = (t >= off) ? sh[t - off] : 0;
        __syncthreads();
        sh[t] += u;
        __syncthreads();
    }
    int ex = ((t == 0) ? 0 : sh[t - 1]) + boff[blockIdx.x];
#pragma unroll
    for (int j = 0; j < 4; ++j) {
        int i = base + j;
        if (i < N) { rowptr[i] = ex; ex += loc[j]; }
    }
}

// Permute edges into CSR slots; store src index and precomputed norm.
__global__ void fill_kernel(const int* __restrict__ src, const int* __restrict__ dst,
                            const float* __restrict__ dinv, const int* __restrict__ rowptr,
                            int* __restrict__ cursor, int* __restrict__ esrc,
                            float* __restrict__ enorm, int E) {
    int e = blockIdx.x * blockDim.x + threadIdx.x;
    if (e >= E) return;
    int d = dst[e], s = src[e];
    int p = rowptr[d] + atomicAdd(&cursor[d], 1);
    esrc[p] = s;
    enorm[p] = dinv[s] * dinv[d];
}

// Y[N,C] = X[N,K] @ W[K,C].  Each block: ROWS rows; each thread: RT rows x 4 cols.
template<int K, int C, int RT>
__global__ __launch_bounds__(256) void gemm_kernel(const float* __restrict__ X,
                                                   const float* __restrict__ W,
                                                   float* __restrict__ Y, int N) {
    constexpr int CG = C / 4;        // col groups (threads per row-group)
    constexpr int RG = 256 / CG;     // row groups
    constexpr int ROWS = RG * RT;    // rows per block
    __shared__ float Wl[K * C];
    __shared__ float Xl[ROWS * (K + 1)];
    const int tid = threadIdx.x;

    for (int i = tid; i < K * C / 4; i += 256)
        ((float4*)Wl)[i] = ((const float4*)W)[i];

    const int row0 = blockIdx.x * ROWS;
    for (int idx = tid; idx < ROWS * (K / 4); idx += 256) {
        int r = idx / (K / 4), kc = idx % (K / 4);
        float4 v = make_float4(0.f, 0.f, 0.f, 0.f);
        int gr = row0 + r;
        if (gr < N) v = ((const float4*)X)[(size_t)gr * (K / 4) + kc];
        float* p = &Xl[r * (K + 1) + kc * 4];
        p[0] = v.x; p[1] = v.y; p[2] = v.z; p[3] = v.w;
    }
    __syncthreads();

    const int cg = tid % CG, rg = tid / CG;
    float acc[RT][4];
#pragma unroll
    for (int j = 0; j < RT; ++j)
#pragma unroll
        for (int c = 0; c < 4; ++c) acc[j][c] = 0.f;

#pragma unroll 4
    for (int k = 0; k < K; ++k) {
        float4 w = *(const float4*)&Wl[k * C + cg * 4];
#pragma unroll
        for (int j = 0; j < RT; ++j) {
            float xv = Xl[(rg * RT + j) * (K + 1) + k];
            acc[j][0] += xv * w.x;
            acc[j][1] += xv * w.y;
            acc[j][2] += xv * w.z;
            acc[j][3] += xv * w.w;
        }
    }

#pragma unroll
    for (int j = 0; j < RT; ++j) {
        int gr = row0 + rg * RT + j;
        if (gr < N)
            *(float4*)&Y[(size_t)gr * C + cg * 4] =
                make_float4(acc[j][0], acc[j][1], acc[j][2], acc[j][3]);
    }
}

// CSR gather aggregation, fused self-loop + bias (+relu).
// C lanes per node; blockDim 256 -> 256/C nodes per block.
template<int C, bool RELU>
__global__ __launch_bounds__(256) void agg_kernel(const float* __restrict__ H,
                                                  const int* __restrict__ rowptr,
                                                  const int* __restrict__ esrc,
                                                  const float* __restrict__ enorm,
                                                  const float* __restrict__ dinv,
                                                  const float* __restrict__ bias,
                                                  float* __restrict__ OUT, int N) {
    constexpr int NPB = 256 / C;
    const int f = threadIdx.x % C;                       // feature lane
    const int node = blockIdx.x * NPB + threadIdx.x / C;
    if (node >= N) return;
    const int lo = rowptr[node], hi = rowptr[node + 1];

    float a0 = 0.f, a1 = 0.f, a2 = 0.f, a3 = 0.f;
    int i = lo;
    for (; i + 4 <= hi; i += 4) {
        int s0 = esrc[i + 0], s1 = esrc[i + 1], s2 = esrc[i + 2], s3 = esrc[i + 3];
        float w0 = enorm[i + 0], w1 = enorm[i + 1], w2 = enorm[i + 2], w3 = enorm[i + 3];
        float h0 = H[(size_t)s0 * C + f];
        float h1 = H[(size_t)s1 * C + f];
        float h2 = H[(size_t)s2 * C + f];
        float h3 = H[(size_t)s3 * C + f];
        a0 = fmaf(h0, w0, a0);
        a1 = fmaf(h1, w1, a1);
        a2 = fmaf(h2, w2, a2);
        a3 = fmaf(h3, w3, a3);
    }
    for (; i < hi; ++i)
        a0 = fmaf(H[(size_t)esrc[i] * C + f], enorm[i], a0);

    float di = dinv[node];
    float r = (a0 + a1) + (a2 + a3)
            + di * di * H[(size_t)node * C + f]
            + bias[f];
    if (RELU) r = fmaxf(r, 0.f);
    OUT[(size_t)node * C + f] = r;
}

extern "C" void kernel_launch(void* const* d_in, const int* in_sizes, int n_in,
                              void* d_out, int out_size, void* d_ws, size_t ws_size,
                              hipStream_t stream) {
    const float* x  = (const float*)d_in[0];
    const int*   ei = (const int*)d_in[1];
    const float* W1 = (const float*)d_in[2];
    const float* b1 = (const float*)d_in[3];
    const float* W2 = (const float*)d_in[4];
    const float* b2 = (const float*)d_in[5];
    const float* W3 = (const float*)d_in[6];
    const float* b3 = (const float*)d_in[7];
    float* out = (float*)d_out;

    const int N = in_sizes[0] / 128;
    const int E = in_sizes[1] / 2;
    const int* src = ei;
    const int* dst = ei + E;
    const int NSCAN = (N + SCAN_CHUNK - 1) / SCAN_CHUNK;   // 98 for N=100000

    auto align = [](size_t v) { return (v + 255) & ~(size_t)255; };
    char* wsb = (char*)d_ws;
    size_t off = 0;
    float* dinv   = (float*)(wsb + off); off += align((size_t)N * 4);
    int*   rowptr = (int*)  (wsb + off); off += align((size_t)(N + 1) * 4);
    int*   degi   = (int*)  (wsb + off); off += align((size_t)N * 4);
    int*   cursor = (int*)  (wsb + off); off += align((size_t)N * 4);
    int*   bsum   = (int*)  (wsb + off); off += align((size_t)NSCAN * 4);
    int*   boff   = (int*)  (wsb + off); off += align((size_t)NSCAN * 4);
    int*   esrc   = (int*)  (wsb + off); off += align((size_t)E * 4);
    float* enorm  = (float*)(wsb + off); off += align((size_t)E * 4);
    float* P      = (float*)(wsb + off); off += align((size_t)N * 64 * 4);
    float* Q      = (float*)(wsb + off);

    // ---- CSR build ----
    hipMemsetAsync(degi, 0, (size_t)N * 4, stream);
    hipMemsetAsync(cursor, 0, (size_t)N * 4, stream);
    count_kernel<<<(E + BLK - 1) / BLK, BLK, 0, stream>>>(dst, degi, E);
    dinv_kernel<<<(N + BLK - 1) / BLK, BLK, 0, stream>>>(degi, dinv, N);
    scanA_kernel<<<NSCAN, 256, 0, stream>>>(degi, bsum, N);
    scanB_kernel<<<1, 256, 0, stream>>>(bsum, boff, rowptr + N, NSCAN);
    scanC_kernel<<<NSCAN, 256, 0, stream>>>(degi, boff, rowptr, N);
    fill_kernel<<<(E + BLK - 1) / BLK, BLK, 0, stream>>>(src, dst, dinv, rowptr, cursor,
                                                         esrc, enorm, E);

    // ---- Layer 1: 128 -> 64, relu ----
    gemm_kernel<128, 64, 2><<<(N + 31) / 32, BLK, 0, stream>>>(x, W1, P, N);
    agg_kernel<64, true><<<(N * 64 + BLK - 1) / BLK, BLK, 0, stream>>>(P, rowptr, esrc, enorm,
                                                                       dinv, b1, Q, N);

    // ---- Layer 2: 64 -> 64, relu ----
    gemm_kernel<64, 64, 4><<<(N + 63) / 64, BLK, 0, stream>>>(Q, W2, P, N);
    agg_kernel<64, true><<<(N * 64 + BLK - 1) / BLK, BLK, 0, stream>>>(P, rowptr, esrc, enorm,
                                                                       dinv, b2, Q, N);

    // ---- Layer 3: 64 -> 32, no relu, write d_out ----
    gemm_kernel<64, 32, 4><<<(N + 127) / 128, BLK, 0, stream>>>(Q, W3, P, N);
    agg_kernel<32, false><<<(N * 32 + BLK - 1) / BLK, BLK, 0, stream>>>(P, rowptr, esrc, enorm,
                                                                        dinv, b3, out, N);
}